// Round 8
// baseline (479.989 us; speedup 1.0000x reference)
//
#include <hip/hip_runtime.h>
#include <hip/hip_bf16.h>
#include <math.h>

#define S_  1024
#define E_  2560
#define H_  32
#define D_  80
#define E3_ 7680
#define M_  2048   // B*S
#define QK_ 5120   // packed Q|K row width in ws

typedef short bf16x8 __attribute__((ext_vector_type(8)));
typedef float f32x4  __attribute__((ext_vector_type(4)));

static __device__ __forceinline__ float bf2f(unsigned short u) {
    unsigned int i = ((unsigned int)u) << 16;
    float f; __builtin_memcpy(&f, &i, 4); return f;
}
static __device__ __forceinline__ unsigned short f2bf(float f) {
    unsigned int i; __builtin_memcpy(&i, &f, 4);
    i += 0x7fffu + ((i >> 16) & 1u);
    return (unsigned short)(i >> 16);
}

// async global->LDS 16B: dest = wave-uniform base + lane*16 (hardware rule)
static __device__ __forceinline__ void gload_lds16(
    const unsigned short* g, unsigned short* l)
{
    __builtin_amdgcn_global_load_lds(
        (const __attribute__((address_space(1))) void*)g,
        (__attribute__((address_space(3))) void*)l, 16, 0, 0);
}

// ---------- pre-pass: fp32 -> bf16 flat convert ----------
__global__ __launch_bounds__(256) void cvt_bf16_kernel(
    const float* __restrict__ in, unsigned short* __restrict__ out, int n8)
{
    int i = (blockIdx.x * 256 + threadIdx.x);
    if (i >= n8) return;
    const float* p = in + (size_t)i * 8;
    float4 a = *(const float4*)p;
    float4 b = *(const float4*)(p + 4);
    union { uint4 v; unsigned short s[8]; } o;
    o.s[0]=f2bf(a.x); o.s[1]=f2bf(a.y); o.s[2]=f2bf(a.z); o.s[3]=f2bf(a.w);
    o.s[4]=f2bf(b.x); o.s[5]=f2bf(b.y); o.s[6]=f2bf(b.z); o.s[7]=f2bf(b.w);
    *(uint4*)(out + (size_t)i * 8) = o.v;
}

// ---------- pre-pass: fp32 [R][C] -> bf16 [C][R] transpose-convert ----------
__global__ __launch_bounds__(256) void transpose_bf16_kernel(
    const float* __restrict__ in, unsigned short* __restrict__ out, int R, int C)
{
    const int t = threadIdx.x;
    const int r0 = blockIdx.y * 64, c0 = blockIdx.x * 64;
    const int r4 = (t >> 4) * 4;
    const int c4 = (t & 15) * 4;
    float4 rows[4];
#pragma unroll
    for (int i = 0; i < 4; ++i)
        rows[i] = *(const float4*)&in[(size_t)(r0 + r4 + i) * C + c0 + c4];
    const float rv[4][4] = {
        {rows[0].x, rows[0].y, rows[0].z, rows[0].w},
        {rows[1].x, rows[1].y, rows[1].z, rows[1].w},
        {rows[2].x, rows[2].y, rows[2].z, rows[2].w},
        {rows[3].x, rows[3].y, rows[3].z, rows[3].w}};
#pragma unroll
    for (int j = 0; j < 4; ++j) {
        ushort4 o;
        o.x = f2bf(rv[0][j]); o.y = f2bf(rv[1][j]);
        o.z = f2bf(rv[2][j]); o.w = f2bf(rv[3][j]);
        *(ushort4*)&out[(size_t)(c0 + c4 + j) * R + r0 + r4] = o;
    }
}

// ---------- MFMA GEMM 256x256xBK64, 8 waves (round-12, QKV; unchanged) ----------
__global__ __launch_bounds__(512, 2) void mfma_gemm256_kernel(
    const unsigned short* __restrict__ A, int lda,   // [M][K] bf16
    const unsigned short* __restrict__ Wt,           // [N][K] bf16
    const float* __restrict__ bias,
    unsigned short* __restrict__ dst0, int sd0,
    unsigned short* __restrict__ dst1, int sd1, int ncut,
    int K)
{
    // [buf][A=0/B=1][row*64 + slot*8 + e] : 2*2*16384 shorts = 128 KB
    __shared__ unsigned short lds[2][2][256 * 64];

    const int t    = threadIdx.x;
    const int lane = t & 63, wave = t >> 6;          // 8 waves
    const int quad = lane >> 4, l15 = lane & 15;
    const int wm   = wave >> 2, wn = wave & 3;       // 2 x 4 wave grid
    const int m0   = blockIdx.y * 256;
    const int n0   = blockIdx.x * 256;

    const int pr = lane >> 3;
    const int ls = ((lane & 7) - pr) & 7;
    const unsigned short* gA[4];
    const unsigned short* gB[4];
#pragma unroll
    for (int i = 0; i < 4; ++i) {
        const int r = wave * 32 + i * 8 + pr;
        gA[i] = A  + (size_t)(m0 + r) * lda + ls * 8;
        gB[i] = Wt + (size_t)(n0 + r) * K   + ls * 8;
    }

    f32x4 acc[8][4];
#pragma unroll
    for (int mf = 0; mf < 8; ++mf)
#pragma unroll
        for (int nf = 0; nf < 4; ++nf) acc[mf][nf] = (f32x4){0.f, 0.f, 0.f, 0.f};

#pragma unroll
    for (int i = 0; i < 4; ++i) {
        gload_lds16(gA[i], &lds[0][0][(wave * 32 + i * 8) * 64]);
        gload_lds16(gB[i], &lds[0][1][(wave * 32 + i * 8) * 64]);
    }

    const int NT = K / 64;
    for (int kt = 0; kt < NT; ++kt) {
        __syncthreads();

        if (kt + 1 < NT) {
            const int nb = (kt + 1) & 1;
            const size_t koff = (size_t)(kt + 1) * 64;
#pragma unroll
            for (int i = 0; i < 4; ++i) {
                gload_lds16(gA[i] + koff, &lds[nb][0][(wave * 32 + i * 8) * 64]);
                gload_lds16(gB[i] + koff, &lds[nb][1][(wave * 32 + i * 8) * 64]);
            }
        }

        const unsigned short* As = &lds[kt & 1][0][0];
        const unsigned short* Bs = &lds[kt & 1][1][0];
#pragma unroll
        for (int kc = 0; kc < 2; ++kc) {
            bf16x8 bfr[4];
#pragma unroll
            for (int nf = 0; nf < 4; ++nf) {
                const int row = wn * 64 + nf * 16 + l15;
                const int ps  = (quad + 4 * kc + (row & 7)) & 7;
                bfr[nf] = *(const bf16x8*)&Bs[row * 64 + ps * 8];
            }
#pragma unroll
            for (int mf = 0; mf < 8; ++mf) {
                const int row = wm * 128 + mf * 16 + l15;
                const int ps  = (quad + 4 * kc + (row & 7)) & 7;
                const bf16x8 af = *(const bf16x8*)&As[row * 64 + ps * 8];
#pragma unroll
                for (int nf = 0; nf < 4; ++nf)
                    acc[mf][nf] = __builtin_amdgcn_mfma_f32_16x16x32_bf16(af, bfr[nf], acc[mf][nf], 0, 0, 0);
            }
        }
    }

#pragma unroll
    for (int nf = 0; nf < 4; ++nf) {
        const int col = n0 + wn * 64 + nf * 16 + l15;
        const float bv = bias[col];
        unsigned short* dst; int sd, cc;
        if (col < ncut) { dst = dst0; sd = sd0; cc = col; }
        else            { dst = dst1; sd = sd1; cc = col - ncut; }
#pragma unroll
        for (int mf = 0; mf < 8; ++mf) {
            const int rowb = m0 + wm * 128 + mf * 16 + quad * 4;
#pragma unroll
            for (int g = 0; g < 4; ++g)
                dst[(size_t)(rowb + g) * sd + cc] = f2bf(acc[mf][nf][g] + bv);
        }
    }
}

// ---------- MFMA GEMM 128x128 (round-10 structure; used for proj) ----------
template <bool OUT_F32>
__global__ __launch_bounds__(256) void mfma_gemm_kernel(
    const unsigned short* __restrict__ A, int lda,
    const unsigned short* __restrict__ Wt,
    const float* __restrict__ bias,
    void* __restrict__ dst0, int sd0,
    void* __restrict__ dst1, int sd1, int ncut,
    int K)
{
    __shared__ unsigned short As[2][128 * 32];
    __shared__ unsigned short Bs[2][128 * 32];
    const int BUFSZ = 128 * 32;

    const int t    = threadIdx.x;
    const int m0   = blockIdx.y * 128;
    const int n0   = blockIdx.x * 128;
    const int lane = t & 63, wave = t >> 6;
    const int quad = lane >> 4, l15 = lane & 15;
    const int mw   = (wave >> 1) * 64;
    const int nw   = (wave & 1) * 64;

    f32x4 acc[4][4];
#pragma unroll
    for (int i = 0; i < 4; ++i)
#pragma unroll
        for (int j = 0; j < 4; ++j) acc[i][j] = (f32x4){0.f, 0.f, 0.f, 0.f};

    const int srow  = lane >> 2;          // 0..15
    const int sslot = (lane & 3) * 8;     // shorts

    const unsigned short* gA0 = A  + (size_t)(m0 + wave * 32 + srow) * lda + sslot;
    const unsigned short* gA1 = gA0 + (size_t)16 * lda;
    const unsigned short* gB0 = Wt + (size_t)(n0 + wave * 32 + srow) * K + sslot;
    const unsigned short* gB1 = gB0 + (size_t)16 * K;
    unsigned short* lA0 = &As[0][(wave * 32) * 32];
    unsigned short* lA1 = lA0 + 16 * 32;
    unsigned short* lB0 = &Bs[0][(wave * 32) * 32];
    unsigned short* lB1 = lB0 + 16 * 32;

    gload_lds16(gA0, lA0);
    gload_lds16(gA1, lA1);
    gload_lds16(gB0, lB0);
    gload_lds16(gB1, lB1);
    __syncthreads();

    int cur = 0;
    for (int k0 = 0; k0 < K; k0 += 32) {
        const int nxt = cur ^ 1;
        if (k0 + 32 < K) {
            gload_lds16(gA0 + k0 + 32, lA0 + nxt * BUFSZ);
            gload_lds16(gA1 + k0 + 32, lA1 + nxt * BUFSZ);
            gload_lds16(gB0 + k0 + 32, lB0 + nxt * BUFSZ);
            gload_lds16(gB1 + k0 + 32, lB1 + nxt * BUFSZ);
        }

        const unsigned short* rA = &As[cur][0];
        const unsigned short* rB = &Bs[cur][0];
        bf16x8 af[4], bfr[4];
#pragma unroll
        for (int i = 0; i < 4; ++i)
            af[i] = *(const bf16x8*)&rA[(mw + i * 16 + l15) * 32 + quad * 8];
#pragma unroll
        for (int j = 0; j < 4; ++j)
            bfr[j] = *(const bf16x8*)&rB[(nw + j * 16 + l15) * 32 + quad * 8];
#pragma unroll
        for (int i = 0; i < 4; ++i)
#pragma unroll
            for (int j = 0; j < 4; ++j)
                acc[i][j] = __builtin_amdgcn_mfma_f32_16x16x32_bf16(af[i], bfr[j], acc[i][j], 0, 0, 0);

        __syncthreads();
        cur = nxt;
    }

#pragma unroll
    for (int j = 0; j < 4; ++j) {
        const int col = n0 + nw + j * 16 + l15;
        const float bv = bias[col];
        if (OUT_F32) {
            float* dst = (float*)dst0;
#pragma unroll
            for (int i = 0; i < 4; ++i) {
                const int rowb = m0 + mw + i * 16 + quad * 4;
#pragma unroll
                for (int g = 0; g < 4; ++g)
                    dst[(size_t)(rowb + g) * sd0 + col] = acc[i][j][g] + bv;
            }
        } else {
            unsigned short* dst; int sd, cc;
            if (col < ncut) { dst = (unsigned short*)dst0; sd = sd0; cc = col; }
            else            { dst = (unsigned short*)dst1; sd = sd1; cc = col - ncut; }
#pragma unroll
            for (int i = 0; i < 4; ++i) {
                const int rowb = m0 + mw + i * 16 + quad * 4;
#pragma unroll
                for (int g = 0; g < 4; ++g)
                    dst[(size_t)(rowb + g) * sd + cc] = f2bf(acc[i][j][g] + bv);
            }
        }
    }
}

// ---------- MFMA fused attention ----------
// Round-13 changes:
//   * __launch_bounds__(256,3): unified reg usage ~156 (104 arch + ~52 acc)
//     fits the 512/3=170 cap -> 3 blocks/CU (was 2). Rounds 1-2's spills were
//     at the 128-reg (256,4) cap; 170 has margin. Tripwire: WRITE_SIZE.
//   * Ps stride 72 -> 76 shorts: P-write quad bases become banks {0,24,16,8}
//     (was {0,16,0,16} -> 4-way conflict); PV ds_read stays <=2-way.
__global__ __launch_bounds__(256, 3) void attn_mfma_kernel(
    unsigned short* __restrict__ qk,         // [2048][5120] bf16: Q [0,2560), K [2560,5120)
    const unsigned short* __restrict__ vsrc, // [2048][2560] bf16 (parked in d_out)
    const float* __restrict__ gmats,
    const float* __restrict__ gphases,
    const float* __restrict__ gamps,
    const float* __restrict__ qphase,
    const float* __restrict__ is_ptr)
{
    __shared__ unsigned short Ks[64 * 104]; // Q tile (prologue) then K tiles; [row][d], pad d 80..96 = 0
    __shared__ unsigned short Vt[80 * 72];  // V^T [d][kj]
    __shared__ unsigned short Ps[64 * 76];  // P [q][kj] bf16, stride 76 (conflict fix)
    __shared__ float cs[240];               // coeffs [3][80]

    const int t    = threadIdx.x;
    const int wave = t >> 6, lane = t & 63;
    const int quad = lane >> 4, l15 = lane & 15;
    // bijective XCD swizzle over 1024 blocks (8 XCDs x 128 chunks)
    const int lin0 = blockIdx.x;
    const int lin  = ((lin0 & 7) << 7) | (lin0 >> 3);
    const int qt = lin & 15;
    const int bh = lin >> 4;
    const int h  = bh & 31;
    const int b  = bh >> 5;

    const float scale = 0.111803398874989485f;   // 1/sqrt(80)
    const float c2    = scale * scale * is_ptr[0] * (1.0f / 3.0f);
    const float cosph = cosf(qphase[h]);

    if (t < 240) {
        int g = t / 80;
        float r0 = gmats[g*4+0] + gmats[g*4+1];
        float r1 = gmats[g*4+2] + gmats[g*4+3];
        cs[t] = (cosf(gphases[t]) * r0 + sinf(gphases[t]) * r1) * gamps[t];
    }

    const int srow = t >> 2;          // staging row 0..63 (wave w stages rows 16w..16w+15)
    const int scg  = (t & 3) * 20;    // staging col group (20 bf16)

    // V staging mapping (kg-inner, conflict-reduced):
    const int vkg  = t & 15;
    const int vdg0 = t >> 4;

    {   // stage Q tile into Ks + zero the d-pad [80,96)
        const unsigned short* qp = qk + (size_t)(b * S_ + qt * 64 + srow) * QK_ + h * D_ + scg;
#pragma unroll
        for (int u = 0; u < 5; ++u)
            *(ushort4*)&Ks[srow * 104 + scg + 4 * u] = *(const ushort4*)(qp + 4 * u);
        *(ushort4*)&Ks[srow * 104 + 80 + (t & 3) * 4] = (ushort4){0, 0, 0, 0};
    }
    __syncthreads();   // cs + Q visible

    // ---- prefetch tile 0 into registers (overlaps afq/afg build) ----
    ushort4 kpre[5];
    ushort4 vpre[8];
    {
        const unsigned short* kp = qk + (size_t)(b * S_ + srow) * QK_ + E_ + h * D_ + scg;
#pragma unroll
        for (int u = 0; u < 5; ++u) kpre[u] = *(const ushort4*)(kp + 4 * u);
        const unsigned short* vb = vsrc + (size_t)(b * S_) * E_ + h * D_;
#pragma unroll
        for (int i = 0; i < 4; ++i)
            vpre[i] = *(const ushort4*)(vb + (size_t)(vkg * 4 + i) * E_ + vdg0 * 4);
        if (t < 64) {
#pragma unroll
            for (int i = 0; i < 4; ++i)
                vpre[4 + i] = *(const ushort4*)(vb + (size_t)(vkg * 4 + i) * E_ + 64 + vdg0 * 4);
        }
    }

    // A-fragments: base Q + 3 coefficient-scaled variants (persist across k-tiles)
    bf16x8 afq[3], afg[3][3];
#pragma unroll
    for (int kc = 0; kc < 3; ++kc)
        afq[kc] = *(const bf16x8*)&Ks[(wave * 16 + l15) * 104 + quad * 8 + kc * 32];
#pragma unroll
    for (int g = 0; g < 3; ++g)
#pragma unroll
        for (int kc = 0; kc < 3; ++kc)
#pragma unroll
            for (int j = 0; j < 8; ++j) {
                int d = kc * 32 + quad * 8 + j;
                float c = (d < 80) ? cs[g * 80 + d] : 0.f;
                afg[g][kc][j] = (short)f2bf(bf2f((unsigned short)afq[kc][j]) * c);
            }

    f32x4 Ov[5];
#pragma unroll
    for (int nf = 0; nf < 5; ++nf) Ov[nf] = (f32x4){0.f, 0.f, 0.f, 0.f};
    float m_r[4] = {-INFINITY, -INFINITY, -INFINITY, -INFINITY};
    float l_r[4] = {0.f, 0.f, 0.f, 0.f};

    for (int kt = 0; kt < 16; ++kt) {
        __syncthreads();   // prev iter's Ks/Vt/Ps reads complete (iter0: Q-frag reads done)

        // ---- write prefetched K tile [kj][d] into Ks (pad stays 0) ----
#pragma unroll
        for (int u = 0; u < 5; ++u)
            *(ushort4*)&Ks[srow * 104 + scg + 4 * u] = kpre[u];

        // ---- write prefetched V^T [d][kj] via 4x4 in-register transpose ----
        {
            const unsigned short rm[4][4] = {
                {vpre[0].x, vpre[0].y, vpre[0].z, vpre[0].w},
                {vpre[1].x, vpre[1].y, vpre[1].z, vpre[1].w},
                {vpre[2].x, vpre[2].y, vpre[2].z, vpre[2].w},
                {vpre[3].x, vpre[3].y, vpre[3].z, vpre[3].w}};
#pragma unroll
            for (int j = 0; j < 4; ++j) {
                ushort4 w = {rm[0][j], rm[1][j], rm[2][j], rm[3][j]};
                *(ushort4*)&Vt[(vdg0 * 4 + j) * 72 + vkg * 4] = w;
            }
        }
        if (t < 64) {
            const unsigned short rm[4][4] = {
                {vpre[4].x, vpre[4].y, vpre[4].z, vpre[4].w},
                {vpre[5].x, vpre[5].y, vpre[5].z, vpre[5].w},
                {vpre[6].x, vpre[6].y, vpre[6].z, vpre[6].w},
                {vpre[7].x, vpre[7].y, vpre[7].z, vpre[7].w}};
#pragma unroll
            for (int j = 0; j < 4; ++j) {
                ushort4 w = {rm[0][j], rm[1][j], rm[2][j], rm[3][j]};
                *(ushort4*)&Vt[(64 + vdg0 * 4 + j) * 72 + vkg * 4] = w;
            }
        }
        __syncthreads();

        // ---- issue next tile's global loads; latency hides under compute ----
        if (kt < 15) {
            const unsigned short* kp = qk + (size_t)(b * S_ + (kt + 1) * 64 + srow) * QK_ + E_ + h * D_ + scg;
#pragma unroll
            for (int u = 0; u < 5; ++u) kpre[u] = *(const ushort4*)(kp + 4 * u);
            const unsigned short* vb = vsrc + (size_t)(b * S_ + (kt + 1) * 64) * E_ + h * D_;
#pragma unroll
            for (int i = 0; i < 4; ++i)
                vpre[i] = *(const ushort4*)(vb + (size_t)(vkg * 4 + i) * E_ + vdg0 * 4);
            if (t < 64) {
#pragma unroll
                for (int i = 0; i < 4; ++i)
                    vpre[4 + i] = *(const ushort4*)(vb + (size_t)(vkg * 4 + i) * E_ + 64 + vdg0 * 4);
            }
        }

        // ---- score MFMAs in two nf-halves: only sacc[4][2] live at once ----
        float p[4][4];   // [nf][r]
        float mx[4] = {-INFINITY, -INFINITY, -INFINITY, -INFINITY};
#pragma unroll
        for (int hf = 0; hf < 2; ++hf) {
            f32x4 sacc[4][2];
#pragma unroll
            for (int v = 0; v < 4; ++v)
#pragma unroll
                for (int n = 0; n < 2; ++n) sacc[v][n] = (f32x4){0.f, 0.f, 0.f, 0.f};
#pragma unroll
            for (int kc = 0; kc < 3; ++kc) {
                bf16x8 bk[2];
#pragma unroll
                for (int n = 0; n < 2; ++n)
                    bk[n] = *(const bf16x8*)&Ks[((hf * 2 + n) * 16 + l15) * 104 + quad * 8 + kc * 32];
#pragma unroll
                for (int n = 0; n < 2; ++n)
                    sacc[0][n] = __builtin_amdgcn_mfma_f32_16x16x32_bf16(afq[kc], bk[n], sacc[0][n], 0, 0, 0);
#pragma unroll
                for (int g = 0; g < 3; ++g)
#pragma unroll
                    for (int n = 0; n < 2; ++n)
                        sacc[1+g][n] = __builtin_amdgcn_mfma_f32_16x16x32_bf16(afg[g][kc], bk[n], sacc[1+g][n], 0, 0, 0);
            }
#pragma unroll
            for (int n = 0; n < 2; ++n)
#pragma unroll
                for (int r = 0; r < 4; ++r) {
                    float s0 = sacc[1][n][r], s1 = sacc[2][n][r], s2 = sacc[3][n][r];
                    float s = fmaf(fmaf(s0, s1, (s0 + s1) * s2), c2, sacc[0][n][r] * scale);
                    p[hf * 2 + n][r] = s;
                    mx[r] = fmaxf(mx[r], s);
                }
        }

        // ---- online softmax (C layout: row=quad*4+r, col=l15+16nf) ----
#pragma unroll
        for (int r = 0; r < 4; ++r) {
            mx[r] = fmaxf(mx[r], __shfl_xor(mx[r], 1));
            mx[r] = fmaxf(mx[r], __shfl_xor(mx[r], 2));
            mx[r] = fmaxf(mx[r], __shfl_xor(mx[r], 4));
            mx[r] = fmaxf(mx[r], __shfl_xor(mx[r], 8));
        }
        float alpha[4];
#pragma unroll
        for (int r = 0; r < 4; ++r) {
            float m_new = fmaxf(m_r[r], mx[r]);
            alpha[r] = __expf(m_r[r] - m_new);
            m_r[r] = m_new;
        }
#pragma unroll
        for (int nf = 0; nf < 4; ++nf)
#pragma unroll
            for (int r = 0; r < 4; ++r)
                p[nf][r] = __expf(p[nf][r] - m_r[r]);
#pragma unroll
        for (int r = 0; r < 4; ++r) {
            float s = p[0][r] + p[1][r] + p[2][r] + p[3][r];
            s += __shfl_xor(s, 1);
            s += __shfl_xor(s, 2);
            s += __shfl_xor(s, 4);
            s += __shfl_xor(s, 8);
            l_r[r] = l_r[r] * alpha[r] + s;
        }

        // ---- write P (bf16) to LDS; own-wave rows only ----
#pragma unroll
        for (int nf = 0; nf < 4; ++nf)
#pragma unroll
            for (int r = 0; r < 4; ++r)
                Ps[(wave * 16 + quad * 4 + r) * 76 + l15 + 16 * nf] = f2bf(p[nf][r]);
        __asm__ volatile("s_waitcnt lgkmcnt(0)" ::: "memory");

        // ---- O rescale + PV MFMAs ----
#pragma unroll
        for (int nf = 0; nf < 5; ++nf)
#pragma unroll
            for (int r = 0; r < 4; ++r) Ov[nf][r] *= alpha[r];

        bf16x8 ap[2];
#pragma unroll
        for (int kc = 0; kc < 2; ++kc)
            ap[kc] = *(const bf16x8*)&Ps[(wave * 16 + l15) * 76 + quad * 8 + kc * 32];
#pragma unroll
        for (int nf = 0; nf < 5; ++nf)
#pragma unroll
            for (int kc = 0; kc < 2; ++kc) {
                bf16x8 bv = *(const bf16x8*)&Vt[(nf * 16 + l15) * 72 + quad * 8 + kc * 32];
                Ov[nf] = __builtin_amdgcn_mfma_f32_16x16x32_bf16(ap[kc], bv, Ov[nf], 0, 0, 0);
            }
    }

    // ---- epilogue: O * cos(phase)/l -> Q section of qk (bf16) ----
    float inv[4];
#pragma unroll
    for (int r = 0; r < 4; ++r) inv[r] = cosph / l_r[r];
#pragma unroll
    for (int nf = 0; nf < 5; ++nf)
#pragma unroll
        for (int r = 0; r < 4; ++r)
            qk[(size_t)(b * S_ + qt * 64 + wave * 16 + quad * 4 + r) * QK_ + h * D_ + nf * 16 + l15]
                = f2bf(Ov[nf][r] * inv[r]);
}

extern "C" void kernel_launch(void* const* d_in, const int* in_sizes, int n_in,
                              void* d_out, int out_size, void* d_ws, size_t ws_size,
                              hipStream_t stream) {
    (void)in_sizes; (void)n_in; (void)out_size; (void)ws_size;
    const float* hidden  = (const float*)d_in[0];
    const float* Wqkv    = (const float*)d_in[1];
    const float* bqkv    = (const float*)d_in[2];
    const float* Wproj   = (const float*)d_in[3];
    const float* bproj   = (const float*)d_in[4];
    const float* gmats   = (const float*)d_in[5];
    const float* gphases = (const float*)d_in[6];
    const float* gamps   = (const float*)d_in[7];
    const float* qphase  = (const float*)d_in[8];
    const float* is_ptr  = (const float*)d_in[9];

    // ws layout (70.8 MB): qk_ws 21.0 MB | h_bf16 10.5 MB | Wt 39.3 MB (reused for Wproj_t)
    unsigned short* qk_ws  = (unsigned short*)d_ws;
    unsigned short* h_bf16 = (unsigned short*)((char*)d_ws + (size_t)M_ * QK_ * 2);
    unsigned short* Wt     = (unsigned short*)((char*)d_ws + (size_t)M_ * QK_ * 2 + (size_t)M_ * E_ * 2);
    unsigned short* v_buf  = (unsigned short*)d_out;   // V bf16 parked in d_out (consumed by attn)

    dim3 blk(256);
    cvt_bf16_kernel<<<dim3((M_ * E_ / 8 + 255) / 256), blk, 0, stream>>>(hidden, h_bf16, M_ * E_ / 8);
    transpose_bf16_kernel<<<dim3(E3_/64, E_/64), blk, 0, stream>>>(Wqkv, Wt, E_, E3_);
    mfma_gemm256_kernel<<<dim3(E3_/256, M_/256), dim3(512), 0, stream>>>(
        h_bf16, E_, Wt, bqkv, qk_ws, QK_, v_buf, E_, QK_, E_);
    attn_mfma_kernel<<<dim3(2 * H_ * (S_/64)), blk, 0, stream>>>(
        qk_ws, v_buf, gmats, gphases, gamps, qphase, is_ptr);
    transpose_bf16_kernel<<<dim3(E_/64, E_/64), blk, 0, stream>>>(Wproj, Wt, E_, E_);
    mfma_gemm_kernel<true><<<dim3(E_/128, M_/128), blk, 0, stream>>>(
        qk_ws, QK_, Wt, bproj, d_out, E_, d_out, E_, E_, E_);
}

// Round 9
// 419.155 us; speedup vs baseline: 1.1451x; 1.1451x over previous
//
#include <hip/hip_runtime.h>
#include <hip/hip_bf16.h>
#include <math.h>

#define S_  1024
#define E_  2560
#define H_  32
#define D_  80
#define E3_ 7680
#define M_  2048   // B*S
#define QK_ 5120   // packed Q|K row width in ws

typedef short bf16x8 __attribute__((ext_vector_type(8)));
typedef float f32x4  __attribute__((ext_vector_type(4)));

static __device__ __forceinline__ float bf2f(unsigned short u) {
    unsigned int i = ((unsigned int)u) << 16;
    float f; __builtin_memcpy(&f, &i, 4); return f;
}
static __device__ __forceinline__ unsigned short f2bf(float f) {
    unsigned int i; __builtin_memcpy(&i, &f, 4);
    i += 0x7fffu + ((i >> 16) & 1u);
    return (unsigned short)(i >> 16);
}

// async global->LDS 16B: dest = wave-uniform base + lane*16 (hardware rule)
static __device__ __forceinline__ void gload_lds16(
    const unsigned short* g, unsigned short* l)
{
    __builtin_amdgcn_global_load_lds(
        (const __attribute__((address_space(1))) void*)g,
        (__attribute__((address_space(3))) void*)l, 16, 0, 0);
}

// ---------- pre-pass: fp32 -> bf16 flat convert ----------
__global__ __launch_bounds__(256) void cvt_bf16_kernel(
    const float* __restrict__ in, unsigned short* __restrict__ out, int n8)
{
    int i = (blockIdx.x * 256 + threadIdx.x);
    if (i >= n8) return;
    const float* p = in + (size_t)i * 8;
    float4 a = *(const float4*)p;
    float4 b = *(const float4*)(p + 4);
    union { uint4 v; unsigned short s[8]; } o;
    o.s[0]=f2bf(a.x); o.s[1]=f2bf(a.y); o.s[2]=f2bf(a.z); o.s[3]=f2bf(a.w);
    o.s[4]=f2bf(b.x); o.s[5]=f2bf(b.y); o.s[6]=f2bf(b.z); o.s[7]=f2bf(b.w);
    *(uint4*)(out + (size_t)i * 8) = o.v;
}

// ---------- pre-pass: fp32 [R][C] -> bf16 [C][R] transpose-convert ----------
__global__ __launch_bounds__(256) void transpose_bf16_kernel(
    const float* __restrict__ in, unsigned short* __restrict__ out, int R, int C)
{
    const int t = threadIdx.x;
    const int r0 = blockIdx.y * 64, c0 = blockIdx.x * 64;
    const int r4 = (t >> 4) * 4;
    const int c4 = (t & 15) * 4;
    float4 rows[4];
#pragma unroll
    for (int i = 0; i < 4; ++i)
        rows[i] = *(const float4*)&in[(size_t)(r0 + r4 + i) * C + c0 + c4];
    const float rv[4][4] = {
        {rows[0].x, rows[0].y, rows[0].z, rows[0].w},
        {rows[1].x, rows[1].y, rows[1].z, rows[1].w},
        {rows[2].x, rows[2].y, rows[2].z, rows[2].w},
        {rows[3].x, rows[3].y, rows[3].z, rows[3].w}};
#pragma unroll
    for (int j = 0; j < 4; ++j) {
        ushort4 o;
        o.x = f2bf(rv[0][j]); o.y = f2bf(rv[1][j]);
        o.z = f2bf(rv[2][j]); o.w = f2bf(rv[3][j]);
        *(ushort4*)&out[(size_t)(c0 + c4 + j) * R + r0 + r4] = o;
    }
}

// ---------- MFMA GEMM 256x256xBK64, 8 waves (round-12, QKV; unchanged) ----------
__global__ __launch_bounds__(512, 2) void mfma_gemm256_kernel(
    const unsigned short* __restrict__ A, int lda,   // [M][K] bf16
    const unsigned short* __restrict__ Wt,           // [N][K] bf16
    const float* __restrict__ bias,
    unsigned short* __restrict__ dst0, int sd0,
    unsigned short* __restrict__ dst1, int sd1, int ncut,
    int K)
{
    // [buf][A=0/B=1][row*64 + slot*8 + e] : 2*2*16384 shorts = 128 KB
    __shared__ unsigned short lds[2][2][256 * 64];

    const int t    = threadIdx.x;
    const int lane = t & 63, wave = t >> 6;          // 8 waves
    const int quad = lane >> 4, l15 = lane & 15;
    const int wm   = wave >> 2, wn = wave & 3;       // 2 x 4 wave grid
    const int m0   = blockIdx.y * 256;
    const int n0   = blockIdx.x * 256;

    const int pr = lane >> 3;
    const int ls = ((lane & 7) - pr) & 7;
    const unsigned short* gA[4];
    const unsigned short* gB[4];
#pragma unroll
    for (int i = 0; i < 4; ++i) {
        const int r = wave * 32 + i * 8 + pr;
        gA[i] = A  + (size_t)(m0 + r) * lda + ls * 8;
        gB[i] = Wt + (size_t)(n0 + r) * K   + ls * 8;
    }

    f32x4 acc[8][4];
#pragma unroll
    for (int mf = 0; mf < 8; ++mf)
#pragma unroll
        for (int nf = 0; nf < 4; ++nf) acc[mf][nf] = (f32x4){0.f, 0.f, 0.f, 0.f};

#pragma unroll
    for (int i = 0; i < 4; ++i) {
        gload_lds16(gA[i], &lds[0][0][(wave * 32 + i * 8) * 64]);
        gload_lds16(gB[i], &lds[0][1][(wave * 32 + i * 8) * 64]);
    }

    const int NT = K / 64;
    for (int kt = 0; kt < NT; ++kt) {
        __syncthreads();

        if (kt + 1 < NT) {
            const int nb = (kt + 1) & 1;
            const size_t koff = (size_t)(kt + 1) * 64;
#pragma unroll
            for (int i = 0; i < 4; ++i) {
                gload_lds16(gA[i] + koff, &lds[nb][0][(wave * 32 + i * 8) * 64]);
                gload_lds16(gB[i] + koff, &lds[nb][1][(wave * 32 + i * 8) * 64]);
            }
        }

        const unsigned short* As = &lds[kt & 1][0][0];
        const unsigned short* Bs = &lds[kt & 1][1][0];
#pragma unroll
        for (int kc = 0; kc < 2; ++kc) {
            bf16x8 bfr[4];
#pragma unroll
            for (int nf = 0; nf < 4; ++nf) {
                const int row = wn * 64 + nf * 16 + l15;
                const int ps  = (quad + 4 * kc + (row & 7)) & 7;
                bfr[nf] = *(const bf16x8*)&Bs[row * 64 + ps * 8];
            }
            __builtin_amdgcn_s_setprio(1);
#pragma unroll
            for (int mf = 0; mf < 8; ++mf) {
                const int row = wm * 128 + mf * 16 + l15;
                const int ps  = (quad + 4 * kc + (row & 7)) & 7;
                const bf16x8 af = *(const bf16x8*)&As[row * 64 + ps * 8];
#pragma unroll
                for (int nf = 0; nf < 4; ++nf)
                    acc[mf][nf] = __builtin_amdgcn_mfma_f32_16x16x32_bf16(af, bfr[nf], acc[mf][nf], 0, 0, 0);
            }
            __builtin_amdgcn_s_setprio(0);
        }
    }

#pragma unroll
    for (int nf = 0; nf < 4; ++nf) {
        const int col = n0 + wn * 64 + nf * 16 + l15;
        const float bv = bias[col];
        unsigned short* dst; int sd, cc;
        if (col < ncut) { dst = dst0; sd = sd0; cc = col; }
        else            { dst = dst1; sd = sd1; cc = col - ncut; }
#pragma unroll
        for (int mf = 0; mf < 8; ++mf) {
            const int rowb = m0 + wm * 128 + mf * 16 + quad * 4;
#pragma unroll
            for (int g = 0; g < 4; ++g)
                dst[(size_t)(rowb + g) * sd + cc] = f2bf(acc[mf][nf][g] + bv);
        }
    }
}

// ---------- MFMA GEMM 128x128 (round-10 structure; used for proj) ----------
template <bool OUT_F32>
__global__ __launch_bounds__(256) void mfma_gemm_kernel(
    const unsigned short* __restrict__ A, int lda,
    const unsigned short* __restrict__ Wt,
    const float* __restrict__ bias,
    void* __restrict__ dst0, int sd0,
    void* __restrict__ dst1, int sd1, int ncut,
    int K)
{
    __shared__ unsigned short As[2][128 * 32];
    __shared__ unsigned short Bs[2][128 * 32];
    const int BUFSZ = 128 * 32;

    const int t    = threadIdx.x;
    const int m0   = blockIdx.y * 128;
    const int n0   = blockIdx.x * 128;
    const int lane = t & 63, wave = t >> 6;
    const int quad = lane >> 4, l15 = lane & 15;
    const int mw   = (wave >> 1) * 64;
    const int nw   = (wave & 1) * 64;

    f32x4 acc[4][4];
#pragma unroll
    for (int i = 0; i < 4; ++i)
#pragma unroll
        for (int j = 0; j < 4; ++j) acc[i][j] = (f32x4){0.f, 0.f, 0.f, 0.f};

    const int srow  = lane >> 2;          // 0..15
    const int sslot = (lane & 3) * 8;     // shorts

    const unsigned short* gA0 = A  + (size_t)(m0 + wave * 32 + srow) * lda + sslot;
    const unsigned short* gA1 = gA0 + (size_t)16 * lda;
    const unsigned short* gB0 = Wt + (size_t)(n0 + wave * 32 + srow) * K + sslot;
    const unsigned short* gB1 = gB0 + (size_t)16 * K;
    unsigned short* lA0 = &As[0][(wave * 32) * 32];
    unsigned short* lA1 = lA0 + 16 * 32;
    unsigned short* lB0 = &Bs[0][(wave * 32) * 32];
    unsigned short* lB1 = lB0 + 16 * 32;

    gload_lds16(gA0, lA0);
    gload_lds16(gA1, lA1);
    gload_lds16(gB0, lB0);
    gload_lds16(gB1, lB1);
    __syncthreads();

    int cur = 0;
    for (int k0 = 0; k0 < K; k0 += 32) {
        const int nxt = cur ^ 1;
        if (k0 + 32 < K) {
            gload_lds16(gA0 + k0 + 32, lA0 + nxt * BUFSZ);
            gload_lds16(gA1 + k0 + 32, lA1 + nxt * BUFSZ);
            gload_lds16(gB0 + k0 + 32, lB0 + nxt * BUFSZ);
            gload_lds16(gB1 + k0 + 32, lB1 + nxt * BUFSZ);
        }

        const unsigned short* rA = &As[cur][0];
        const unsigned short* rB = &Bs[cur][0];
        bf16x8 af[4], bfr[4];
#pragma unroll
        for (int i = 0; i < 4; ++i)
            af[i] = *(const bf16x8*)&rA[(mw + i * 16 + l15) * 32 + quad * 8];
#pragma unroll
        for (int j = 0; j < 4; ++j)
            bfr[j] = *(const bf16x8*)&rB[(nw + j * 16 + l15) * 32 + quad * 8];
#pragma unroll
        for (int i = 0; i < 4; ++i)
#pragma unroll
            for (int j = 0; j < 4; ++j)
                acc[i][j] = __builtin_amdgcn_mfma_f32_16x16x32_bf16(af[i], bfr[j], acc[i][j], 0, 0, 0);

        __syncthreads();
        cur = nxt;
    }

#pragma unroll
    for (int j = 0; j < 4; ++j) {
        const int col = n0 + nw + j * 16 + l15;
        const float bv = bias[col];
        if (OUT_F32) {
            float* dst = (float*)dst0;
#pragma unroll
            for (int i = 0; i < 4; ++i) {
                const int rowb = m0 + mw + i * 16 + quad * 4;
#pragma unroll
                for (int g = 0; g < 4; ++g)
                    dst[(size_t)(rowb + g) * sd0 + col] = acc[i][j][g] + bv;
            }
        } else {
            unsigned short* dst; int sd, cc;
            if (col < ncut) { dst = (unsigned short*)dst0; sd = sd0; cc = col; }
            else            { dst = (unsigned short*)dst1; sd = sd1; cc = col - ncut; }
#pragma unroll
            for (int i = 0; i < 4; ++i) {
                const int rowb = m0 + mw + i * 16 + quad * 4;
#pragma unroll
                for (int g = 0; g < 4; ++g)
                    dst[(size_t)(rowb + g) * sd + cc] = f2bf(acc[i][j][g] + bv);
            }
        }
    }
}

// ---------- MFMA fused attention ----------
// Round-14: REVERT launch bounds to the proven (256,2) — (256,3) spilled
// (round-8: VGPR capped 84, WRITE 10->32MB, 113->177us). Kernel needs >170
// unified regs; 2 blocks/CU is its operating point. Kept: Ps stride 76
// (conflicts 7.75e6->7.23e6 measured) + T5 s_setprio around MFMA clusters
// (m191: +4-7% attn when co-resident blocks run at different phases).
__global__ __launch_bounds__(256, 2) void attn_mfma_kernel(
    unsigned short* __restrict__ qk,         // [2048][5120] bf16: Q [0,2560), K [2560,5120)
    const unsigned short* __restrict__ vsrc, // [2048][2560] bf16 (parked in d_out)
    const float* __restrict__ gmats,
    const float* __restrict__ gphases,
    const float* __restrict__ gamps,
    const float* __restrict__ qphase,
    const float* __restrict__ is_ptr)
{
    __shared__ unsigned short Ks[64 * 104]; // Q tile (prologue) then K tiles; [row][d], pad d 80..96 = 0
    __shared__ unsigned short Vt[80 * 72];  // V^T [d][kj]
    __shared__ unsigned short Ps[64 * 76];  // P [q][kj] bf16, stride 76 (conflict fix)
    __shared__ float cs[240];               // coeffs [3][80]

    const int t    = threadIdx.x;
    const int wave = t >> 6, lane = t & 63;
    const int quad = lane >> 4, l15 = lane & 15;
    // bijective XCD swizzle over 1024 blocks (8 XCDs x 128 chunks)
    const int lin0 = blockIdx.x;
    const int lin  = ((lin0 & 7) << 7) | (lin0 >> 3);
    const int qt = lin & 15;
    const int bh = lin >> 4;
    const int h  = bh & 31;
    const int b  = bh >> 5;

    const float scale = 0.111803398874989485f;   // 1/sqrt(80)
    const float c2    = scale * scale * is_ptr[0] * (1.0f / 3.0f);
    const float cosph = cosf(qphase[h]);

    if (t < 240) {
        int g = t / 80;
        float r0 = gmats[g*4+0] + gmats[g*4+1];
        float r1 = gmats[g*4+2] + gmats[g*4+3];
        cs[t] = (cosf(gphases[t]) * r0 + sinf(gphases[t]) * r1) * gamps[t];
    }

    const int srow = t >> 2;          // staging row 0..63 (wave w stages rows 16w..16w+15)
    const int scg  = (t & 3) * 20;    // staging col group (20 bf16)

    // V staging mapping (kg-inner, conflict-reduced):
    const int vkg  = t & 15;
    const int vdg0 = t >> 4;

    {   // stage Q tile into Ks + zero the d-pad [80,96)
        const unsigned short* qp = qk + (size_t)(b * S_ + qt * 64 + srow) * QK_ + h * D_ + scg;
#pragma unroll
        for (int u = 0; u < 5; ++u)
            *(ushort4*)&Ks[srow * 104 + scg + 4 * u] = *(const ushort4*)(qp + 4 * u);
        *(ushort4*)&Ks[srow * 104 + 80 + (t & 3) * 4] = (ushort4){0, 0, 0, 0};
    }
    __syncthreads();   // cs + Q visible

    // ---- prefetch tile 0 into registers (overlaps afq/afg build) ----
    ushort4 kpre[5];
    ushort4 vpre[8];
    {
        const unsigned short* kp = qk + (size_t)(b * S_ + srow) * QK_ + E_ + h * D_ + scg;
#pragma unroll
        for (int u = 0; u < 5; ++u) kpre[u] = *(const ushort4*)(kp + 4 * u);
        const unsigned short* vb = vsrc + (size_t)(b * S_) * E_ + h * D_;
#pragma unroll
        for (int i = 0; i < 4; ++i)
            vpre[i] = *(const ushort4*)(vb + (size_t)(vkg * 4 + i) * E_ + vdg0 * 4);
        if (t < 64) {
#pragma unroll
            for (int i = 0; i < 4; ++i)
                vpre[4 + i] = *(const ushort4*)(vb + (size_t)(vkg * 4 + i) * E_ + 64 + vdg0 * 4);
        }
    }

    // A-fragments: base Q + 3 coefficient-scaled variants (persist across k-tiles)
    bf16x8 afq[3], afg[3][3];
#pragma unroll
    for (int kc = 0; kc < 3; ++kc)
        afq[kc] = *(const bf16x8*)&Ks[(wave * 16 + l15) * 104 + quad * 8 + kc * 32];
#pragma unroll
    for (int g = 0; g < 3; ++g)
#pragma unroll
        for (int kc = 0; kc < 3; ++kc)
#pragma unroll
            for (int j = 0; j < 8; ++j) {
                int d = kc * 32 + quad * 8 + j;
                float c = (d < 80) ? cs[g * 80 + d] : 0.f;
                afg[g][kc][j] = (short)f2bf(bf2f((unsigned short)afq[kc][j]) * c);
            }

    f32x4 Ov[5];
#pragma unroll
    for (int nf = 0; nf < 5; ++nf) Ov[nf] = (f32x4){0.f, 0.f, 0.f, 0.f};
    float m_r[4] = {-INFINITY, -INFINITY, -INFINITY, -INFINITY};
    float l_r[4] = {0.f, 0.f, 0.f, 0.f};

    for (int kt = 0; kt < 16; ++kt) {
        __syncthreads();   // prev iter's Ks/Vt/Ps reads complete (iter0: Q-frag reads done)

        // ---- write prefetched K tile [kj][d] into Ks (pad stays 0) ----
#pragma unroll
        for (int u = 0; u < 5; ++u)
            *(ushort4*)&Ks[srow * 104 + scg + 4 * u] = kpre[u];

        // ---- write prefetched V^T [d][kj] via 4x4 in-register transpose ----
        {
            const unsigned short rm[4][4] = {
                {vpre[0].x, vpre[0].y, vpre[0].z, vpre[0].w},
                {vpre[1].x, vpre[1].y, vpre[1].z, vpre[1].w},
                {vpre[2].x, vpre[2].y, vpre[2].z, vpre[2].w},
                {vpre[3].x, vpre[3].y, vpre[3].z, vpre[3].w}};
#pragma unroll
            for (int j = 0; j < 4; ++j) {
                ushort4 w = {rm[0][j], rm[1][j], rm[2][j], rm[3][j]};
                *(ushort4*)&Vt[(vdg0 * 4 + j) * 72 + vkg * 4] = w;
            }
        }
        if (t < 64) {
            const unsigned short rm[4][4] = {
                {vpre[4].x, vpre[4].y, vpre[4].z, vpre[4].w},
                {vpre[5].x, vpre[5].y, vpre[5].z, vpre[5].w},
                {vpre[6].x, vpre[6].y, vpre[6].z, vpre[6].w},
                {vpre[7].x, vpre[7].y, vpre[7].z, vpre[7].w}};
#pragma unroll
            for (int j = 0; j < 4; ++j) {
                ushort4 w = {rm[0][j], rm[1][j], rm[2][j], rm[3][j]};
                *(ushort4*)&Vt[(64 + vdg0 * 4 + j) * 72 + vkg * 4] = w;
            }
        }
        __syncthreads();

        // ---- issue next tile's global loads; latency hides under compute ----
        if (kt < 15) {
            const unsigned short* kp = qk + (size_t)(b * S_ + (kt + 1) * 64 + srow) * QK_ + E_ + h * D_ + scg;
#pragma unroll
            for (int u = 0; u < 5; ++u) kpre[u] = *(const ushort4*)(kp + 4 * u);
            const unsigned short* vb = vsrc + (size_t)(b * S_ + (kt + 1) * 64) * E_ + h * D_;
#pragma unroll
            for (int i = 0; i < 4; ++i)
                vpre[i] = *(const ushort4*)(vb + (size_t)(vkg * 4 + i) * E_ + vdg0 * 4);
            if (t < 64) {
#pragma unroll
                for (int i = 0; i < 4; ++i)
                    vpre[4 + i] = *(const ushort4*)(vb + (size_t)(vkg * 4 + i) * E_ + 64 + vdg0 * 4);
            }
        }

        // ---- score MFMAs in two nf-halves: only sacc[4][2] live at once ----
        float p[4][4];   // [nf][r]
        float mx[4] = {-INFINITY, -INFINITY, -INFINITY, -INFINITY};
#pragma unroll
        for (int hf = 0; hf < 2; ++hf) {
            f32x4 sacc[4][2];
#pragma unroll
            for (int v = 0; v < 4; ++v)
#pragma unroll
                for (int n = 0; n < 2; ++n) sacc[v][n] = (f32x4){0.f, 0.f, 0.f, 0.f};
#pragma unroll
            for (int kc = 0; kc < 3; ++kc) {
                bf16x8 bk[2];
#pragma unroll
                for (int n = 0; n < 2; ++n)
                    bk[n] = *(const bf16x8*)&Ks[((hf * 2 + n) * 16 + l15) * 104 + quad * 8 + kc * 32];
                __builtin_amdgcn_s_setprio(1);
#pragma unroll
                for (int n = 0; n < 2; ++n)
                    sacc[0][n] = __builtin_amdgcn_mfma_f32_16x16x32_bf16(afq[kc], bk[n], sacc[0][n], 0, 0, 0);
#pragma unroll
                for (int g = 0; g < 3; ++g)
#pragma unroll
                    for (int n = 0; n < 2; ++n)
                        sacc[1+g][n] = __builtin_amdgcn_mfma_f32_16x16x32_bf16(afg[g][kc], bk[n], sacc[1+g][n], 0, 0, 0);
                __builtin_amdgcn_s_setprio(0);
            }
#pragma unroll
            for (int n = 0; n < 2; ++n)
#pragma unroll
                for (int r = 0; r < 4; ++r) {
                    float s0 = sacc[1][n][r], s1 = sacc[2][n][r], s2 = sacc[3][n][r];
                    float s = fmaf(fmaf(s0, s1, (s0 + s1) * s2), c2, sacc[0][n][r] * scale);
                    p[hf * 2 + n][r] = s;
                    mx[r] = fmaxf(mx[r], s);
                }
        }

        // ---- online softmax (C layout: row=quad*4+r, col=l15+16nf) ----
#pragma unroll
        for (int r = 0; r < 4; ++r) {
            mx[r] = fmaxf(mx[r], __shfl_xor(mx[r], 1));
            mx[r] = fmaxf(mx[r], __shfl_xor(mx[r], 2));
            mx[r] = fmaxf(mx[r], __shfl_xor(mx[r], 4));
            mx[r] = fmaxf(mx[r], __shfl_xor(mx[r], 8));
        }
        float alpha[4];
#pragma unroll
        for (int r = 0; r < 4; ++r) {
            float m_new = fmaxf(m_r[r], mx[r]);
            alpha[r] = __expf(m_r[r] - m_new);
            m_r[r] = m_new;
        }
#pragma unroll
        for (int nf = 0; nf < 4; ++nf)
#pragma unroll
            for (int r = 0; r < 4; ++r)
                p[nf][r] = __expf(p[nf][r] - m_r[r]);
#pragma unroll
        for (int r = 0; r < 4; ++r) {
            float s = p[0][r] + p[1][r] + p[2][r] + p[3][r];
            s += __shfl_xor(s, 1);
            s += __shfl_xor(s, 2);
            s += __shfl_xor(s, 4);
            s += __shfl_xor(s, 8);
            l_r[r] = l_r[r] * alpha[r] + s;
        }

        // ---- write P (bf16) to LDS; own-wave rows only ----
#pragma unroll
        for (int nf = 0; nf < 4; ++nf)
#pragma unroll
            for (int r = 0; r < 4; ++r)
                Ps[(wave * 16 + quad * 4 + r) * 76 + l15 + 16 * nf] = f2bf(p[nf][r]);
        __asm__ volatile("s_waitcnt lgkmcnt(0)" ::: "memory");

        // ---- O rescale + PV MFMAs ----
#pragma unroll
        for (int nf = 0; nf < 5; ++nf)
#pragma unroll
            for (int r = 0; r < 4; ++r) Ov[nf][r] *= alpha[r];

        bf16x8 ap[2];
#pragma unroll
        for (int kc = 0; kc < 2; ++kc)
            ap[kc] = *(const bf16x8*)&Ps[(wave * 16 + l15) * 76 + quad * 8 + kc * 32];
        __builtin_amdgcn_s_setprio(1);
#pragma unroll
        for (int nf = 0; nf < 5; ++nf)
#pragma unroll
            for (int kc = 0; kc < 2; ++kc) {
                bf16x8 bv = *(const bf16x8*)&Vt[(nf * 16 + l15) * 72 + quad * 8 + kc * 32];
                Ov[nf] = __builtin_amdgcn_mfma_f32_16x16x32_bf16(ap[kc], bv, Ov[nf], 0, 0, 0);
            }
        __builtin_amdgcn_s_setprio(0);
    }

    // ---- epilogue: O * cos(phase)/l -> Q section of qk (bf16) ----
    float inv[4];
#pragma unroll
    for (int r = 0; r < 4; ++r) inv[r] = cosph / l_r[r];
#pragma unroll
    for (int nf = 0; nf < 5; ++nf)
#pragma unroll
        for (int r = 0; r < 4; ++r)
            qk[(size_t)(b * S_ + qt * 64 + wave * 16 + quad * 4 + r) * QK_ + h * D_ + nf * 16 + l15]
                = f2bf(Ov[nf][r] * inv[r]);
}

extern "C" void kernel_launch(void* const* d_in, const int* in_sizes, int n_in,
                              void* d_out, int out_size, void* d_ws, size_t ws_size,
                              hipStream_t stream) {
    (void)in_sizes; (void)n_in; (void)out_size; (void)ws_size;
    const float* hidden  = (const float*)d_in[0];
    const float* Wqkv    = (const float*)d_in[1];
    const float* bqkv    = (const float*)d_in[2];
    const float* Wproj   = (const float*)d_in[3];
    const float* bproj   = (const float*)d_in[4];
    const float* gmats   = (const float*)d_in[5];
    const float* gphases = (const float*)d_in[6];
    const float* gamps   = (const float*)d_in[7];
    const float* qphase  = (const float*)d_in[8];
    const float* is_ptr  = (const float*)d_in[9];

    // ws layout (70.8 MB): qk_ws 21.0 MB | h_bf16 10.5 MB | Wt 39.3 MB (reused for Wproj_t)
    unsigned short* qk_ws  = (unsigned short*)d_ws;
    unsigned short* h_bf16 = (unsigned short*)((char*)d_ws + (size_t)M_ * QK_ * 2);
    unsigned short* Wt     = (unsigned short*)((char*)d_ws + (size_t)M_ * QK_ * 2 + (size_t)M_ * E_ * 2);
    unsigned short* v_buf  = (unsigned short*)d_out;   // V bf16 parked in d_out (consumed by attn)

    dim3 blk(256);
    cvt_bf16_kernel<<<dim3((M_ * E_ / 8 + 255) / 256), blk, 0, stream>>>(hidden, h_bf16, M_ * E_ / 8);
    transpose_bf16_kernel<<<dim3(E3_/64, E_/64), blk, 0, stream>>>(Wqkv, Wt, E_, E3_);
    mfma_gemm256_kernel<<<dim3(E3_/256, M_/256), dim3(512), 0, stream>>>(
        h_bf16, E_, Wt, bqkv, qk_ws, QK_, v_buf, E_, QK_, E_);
    attn_mfma_kernel<<<dim3(2 * H_ * (S_/64)), blk, 0, stream>>>(
        qk_ws, v_buf, gmats, gphases, gamps, qphase, is_ptr);
    transpose_bf16_kernel<<<dim3(E_/64, E_/64), blk, 0, stream>>>(Wproj, Wt, E_, E_);
    mfma_gemm_kernel<true><<<dim3(E_/128, M_/128), blk, 0, stream>>>(
        qk_ws, QK_, Wt, bproj, d_out, E_, d_out, E_, E_, E_);
}

// Round 10
// 388.358 us; speedup vs baseline: 1.2359x; 1.0793x over previous
//
#include <hip/hip_runtime.h>
#include <hip/hip_bf16.h>
#include <math.h>

#define S_  1024
#define E_  2560
#define H_  32
#define D_  80
#define E3_ 7680
#define M_  2048   // B*S
#define QK_ 5120   // packed Q|K row width in ws

typedef short bf16x8 __attribute__((ext_vector_type(8)));
typedef float f32x4  __attribute__((ext_vector_type(4)));

static __device__ __forceinline__ float bf2f(unsigned short u) {
    unsigned int i = ((unsigned int)u) << 16;
    float f; __builtin_memcpy(&f, &i, 4); return f;
}
static __device__ __forceinline__ unsigned short f2bf(float f) {
    unsigned int i; __builtin_memcpy(&i, &f, 4);
    i += 0x7fffu + ((i >> 16) & 1u);
    return (unsigned short)(i >> 16);
}

// async global->LDS 16B: dest = wave-uniform base + lane*16 (hardware rule)
static __device__ __forceinline__ void gload_lds16(
    const unsigned short* g, unsigned short* l)
{
    __builtin_amdgcn_global_load_lds(
        (const __attribute__((address_space(1))) void*)g,
        (__attribute__((address_space(3))) void*)l, 16, 0, 0);
}

// ---------- pre-pass: fp32 -> bf16 flat convert ----------
__global__ __launch_bounds__(256) void cvt_bf16_kernel(
    const float* __restrict__ in, unsigned short* __restrict__ out, int n8)
{
    int i = (blockIdx.x * 256 + threadIdx.x);
    if (i >= n8) return;
    const float* p = in + (size_t)i * 8;
    float4 a = *(const float4*)p;
    float4 b = *(const float4*)(p + 4);
    union { uint4 v; unsigned short s[8]; } o;
    o.s[0]=f2bf(a.x); o.s[1]=f2bf(a.y); o.s[2]=f2bf(a.z); o.s[3]=f2bf(a.w);
    o.s[4]=f2bf(b.x); o.s[5]=f2bf(b.y); o.s[6]=f2bf(b.z); o.s[7]=f2bf(b.w);
    *(uint4*)(out + (size_t)i * 8) = o.v;
}

// ---------- pre-pass: fp32 [R][C] -> bf16 [C][R] transpose-convert ----------
// Round-15 rewrite: LDS-tiled so BOTH global sides are coalesced. The old
// version wrote 8B/lane at stride 8R bytes -> one 64B sector per 8B store
// (~8x write amplification, ~314MB effective on Wqkv). Now: float4 coalesced
// reads -> cvt -> LDS [64][74] bf16 (pad 74 => <=2-way bank aliasing) ->
// uint4 coalesced writes.
__global__ __launch_bounds__(256) void transpose_bf16_kernel(
    const float* __restrict__ in, unsigned short* __restrict__ out, int R, int C)
{
    __shared__ unsigned short tile[64][74];
    const int t  = threadIdx.x;
    const int r0 = blockIdx.y * 64, c0 = blockIdx.x * 64;
    const int rr = t >> 4;          // 0..15
    const int c4 = (t & 15) * 4;    // 0..60
#pragma unroll
    for (int p = 0; p < 4; ++p) {
        const int r = rr + p * 16;
        float4 v = *(const float4*)&in[(size_t)(r0 + r) * C + c0 + c4];
        tile[c4 + 0][r] = f2bf(v.x);
        tile[c4 + 1][r] = f2bf(v.y);
        tile[c4 + 2][r] = f2bf(v.z);
        tile[c4 + 3][r] = f2bf(v.w);
    }
    __syncthreads();
    const int orow = t >> 3;        // 0..31
    const int ocol = (t & 7) * 8;   // 0..56
#pragma unroll
    for (int p = 0; p < 2; ++p) {
        const int c = orow + p * 32;
        *(uint4*)&out[(size_t)(c0 + c) * R + r0 + ocol] = *(const uint4*)&tile[c][ocol];
    }
}

// ---------- MFMA GEMM 256x256xBK64, 8 waves (round-12, QKV; round-7 state) ----------
__global__ __launch_bounds__(512, 2) void mfma_gemm256_kernel(
    const unsigned short* __restrict__ A, int lda,   // [M][K] bf16
    const unsigned short* __restrict__ Wt,           // [N][K] bf16
    const float* __restrict__ bias,
    unsigned short* __restrict__ dst0, int sd0,
    unsigned short* __restrict__ dst1, int sd1, int ncut,
    int K)
{
    // [buf][A=0/B=1][row*64 + slot*8 + e] : 2*2*16384 shorts = 128 KB
    __shared__ unsigned short lds[2][2][256 * 64];

    const int t    = threadIdx.x;
    const int lane = t & 63, wave = t >> 6;          // 8 waves
    const int quad = lane >> 4, l15 = lane & 15;
    const int wm   = wave >> 2, wn = wave & 3;       // 2 x 4 wave grid
    const int m0   = blockIdx.y * 256;
    const int n0   = blockIdx.x * 256;

    const int pr = lane >> 3;
    const int ls = ((lane & 7) - pr) & 7;
    const unsigned short* gA[4];
    const unsigned short* gB[4];
#pragma unroll
    for (int i = 0; i < 4; ++i) {
        const int r = wave * 32 + i * 8 + pr;
        gA[i] = A  + (size_t)(m0 + r) * lda + ls * 8;
        gB[i] = Wt + (size_t)(n0 + r) * K   + ls * 8;
    }

    f32x4 acc[8][4];
#pragma unroll
    for (int mf = 0; mf < 8; ++mf)
#pragma unroll
        for (int nf = 0; nf < 4; ++nf) acc[mf][nf] = (f32x4){0.f, 0.f, 0.f, 0.f};

#pragma unroll
    for (int i = 0; i < 4; ++i) {
        gload_lds16(gA[i], &lds[0][0][(wave * 32 + i * 8) * 64]);
        gload_lds16(gB[i], &lds[0][1][(wave * 32 + i * 8) * 64]);
    }

    const int NT = K / 64;
    for (int kt = 0; kt < NT; ++kt) {
        __syncthreads();

        if (kt + 1 < NT) {
            const int nb = (kt + 1) & 1;
            const size_t koff = (size_t)(kt + 1) * 64;
#pragma unroll
            for (int i = 0; i < 4; ++i) {
                gload_lds16(gA[i] + koff, &lds[nb][0][(wave * 32 + i * 8) * 64]);
                gload_lds16(gB[i] + koff, &lds[nb][1][(wave * 32 + i * 8) * 64]);
            }
        }

        const unsigned short* As = &lds[kt & 1][0][0];
        const unsigned short* Bs = &lds[kt & 1][1][0];
#pragma unroll
        for (int kc = 0; kc < 2; ++kc) {
            bf16x8 bfr[4];
#pragma unroll
            for (int nf = 0; nf < 4; ++nf) {
                const int row = wn * 64 + nf * 16 + l15;
                const int ps  = (quad + 4 * kc + (row & 7)) & 7;
                bfr[nf] = *(const bf16x8*)&Bs[row * 64 + ps * 8];
            }
#pragma unroll
            for (int mf = 0; mf < 8; ++mf) {
                const int row = wm * 128 + mf * 16 + l15;
                const int ps  = (quad + 4 * kc + (row & 7)) & 7;
                const bf16x8 af = *(const bf16x8*)&As[row * 64 + ps * 8];
#pragma unroll
                for (int nf = 0; nf < 4; ++nf)
                    acc[mf][nf] = __builtin_amdgcn_mfma_f32_16x16x32_bf16(af, bfr[nf], acc[mf][nf], 0, 0, 0);
            }
        }
    }

#pragma unroll
    for (int nf = 0; nf < 4; ++nf) {
        const int col = n0 + wn * 64 + nf * 16 + l15;
        const float bv = bias[col];
        unsigned short* dst; int sd, cc;
        if (col < ncut) { dst = dst0; sd = sd0; cc = col; }
        else            { dst = dst1; sd = sd1; cc = col - ncut; }
#pragma unroll
        for (int mf = 0; mf < 8; ++mf) {
            const int rowb = m0 + wm * 128 + mf * 16 + quad * 4;
#pragma unroll
            for (int g = 0; g < 4; ++g)
                dst[(size_t)(rowb + g) * sd + cc] = f2bf(acc[mf][nf][g] + bv);
        }
    }
}

// ---------- MFMA GEMM proj: 128x128, 512 threads, BK=64 (round-15) ----------
// Old proj (128x128, 256 thr, BK=32) had a 620-cyc window and ~110us. New:
// 8 waves (2x4: wave owns 64x32), BK=64 double-buffered gload_lds with the
// slot-rotation swizzle proven in the 256^2 kernel. LDS 64KB -> 2 blocks/CU;
// grid 320 blocks. fp32 output + bias.
__global__ __launch_bounds__(512) void mfma_gemm_proj_kernel(
    const unsigned short* __restrict__ A, int lda,   // [M][K] bf16 (Q section of qk_ws)
    const unsigned short* __restrict__ Wt,           // [N][K] bf16
    const float* __restrict__ bias,
    float* __restrict__ dst, int sd,
    int K)
{
    // [buf][A=0/B=1][row*64 + slot*8 + e] : 2*2*8192 shorts = 64 KB
    __shared__ unsigned short lds[2][2][128 * 64];

    const int t    = threadIdx.x;
    const int lane = t & 63, wave = t >> 6;          // 8 waves
    const int quad = lane >> 4, l15 = lane & 15;
    const int wm   = wave >> 2, wn = wave & 3;       // 2 x 4 wave grid
    const int m0   = blockIdx.y * 128;
    const int n0   = blockIdx.x * 128;

    // staging: wave stages rows [16w,16w+16) of A and B tiles; instr i covers
    // 8 rows; lane l: row-in-chunk pr=l>>3, logical slot ls=((l&7)-pr)&7.
    const int pr = lane >> 3;
    const int ls = ((lane & 7) - pr) & 7;
    const unsigned short* gA[2];
    const unsigned short* gB[2];
#pragma unroll
    for (int i = 0; i < 2; ++i) {
        const int r = wave * 16 + i * 8 + pr;
        gA[i] = A  + (size_t)(m0 + r) * lda + ls * 8;
        gB[i] = Wt + (size_t)(n0 + r) * K   + ls * 8;
    }

    f32x4 acc[4][2];
#pragma unroll
    for (int mf = 0; mf < 4; ++mf)
#pragma unroll
        for (int nf = 0; nf < 2; ++nf) acc[mf][nf] = (f32x4){0.f, 0.f, 0.f, 0.f};

#pragma unroll
    for (int i = 0; i < 2; ++i) {
        gload_lds16(gA[i], &lds[0][0][(wave * 16 + i * 8) * 64]);
        gload_lds16(gB[i], &lds[0][1][(wave * 16 + i * 8) * 64]);
    }

    const int NT = K / 64;   // 40
    for (int kt = 0; kt < NT; ++kt) {
        __syncthreads();

        if (kt + 1 < NT) {
            const int nb = (kt + 1) & 1;
            const size_t koff = (size_t)(kt + 1) * 64;
#pragma unroll
            for (int i = 0; i < 2; ++i) {
                gload_lds16(gA[i] + koff, &lds[nb][0][(wave * 16 + i * 8) * 64]);
                gload_lds16(gB[i] + koff, &lds[nb][1][(wave * 16 + i * 8) * 64]);
            }
        }

        const unsigned short* As = &lds[kt & 1][0][0];
        const unsigned short* Bs = &lds[kt & 1][1][0];
#pragma unroll
        for (int kc = 0; kc < 2; ++kc) {
            bf16x8 bfr[2];
#pragma unroll
            for (int nf = 0; nf < 2; ++nf) {
                const int row = wn * 32 + nf * 16 + l15;
                const int ps  = (quad + 4 * kc + (row & 7)) & 7;
                bfr[nf] = *(const bf16x8*)&Bs[row * 64 + ps * 8];
            }
#pragma unroll
            for (int mf = 0; mf < 4; ++mf) {
                const int row = wm * 64 + mf * 16 + l15;
                const int ps  = (quad + 4 * kc + (row & 7)) & 7;
                const bf16x8 af = *(const bf16x8*)&As[row * 64 + ps * 8];
#pragma unroll
                for (int nf = 0; nf < 2; ++nf)
                    acc[mf][nf] = __builtin_amdgcn_mfma_f32_16x16x32_bf16(af, bfr[nf], acc[mf][nf], 0, 0, 0);
            }
        }
    }

#pragma unroll
    for (int nf = 0; nf < 2; ++nf) {
        const int col = n0 + wn * 32 + nf * 16 + l15;
        const float bv = bias[col];
#pragma unroll
        for (int mf = 0; mf < 4; ++mf) {
            const int rowb = m0 + wm * 64 + mf * 16 + quad * 4;
#pragma unroll
            for (int g = 0; g < 4; ++g)
                dst[(size_t)(rowb + g) * sd + col] = acc[mf][nf][g] + bv;
        }
    }
}

// ---------- MFMA fused attention (round-11 exact — measured best 113.4us) ----------
__global__ __launch_bounds__(256, 2) void attn_mfma_kernel(
    unsigned short* __restrict__ qk,         // [2048][5120] bf16: Q [0,2560), K [2560,5120)
    const unsigned short* __restrict__ vsrc, // [2048][2560] bf16 (parked in d_out)
    const float* __restrict__ gmats,
    const float* __restrict__ gphases,
    const float* __restrict__ gamps,
    const float* __restrict__ qphase,
    const float* __restrict__ is_ptr)
{
    __shared__ unsigned short Ks[64 * 104]; // Q tile (prologue) then K tiles; [row][d], pad d 80..96 = 0
    __shared__ unsigned short Vt[80 * 72];  // V^T [d][kj]
    __shared__ unsigned short Ps[64 * 72];  // P [q][kj] bf16
    __shared__ float cs[240];               // coeffs [3][80]

    const int t    = threadIdx.x;
    const int wave = t >> 6, lane = t & 63;
    const int quad = lane >> 4, l15 = lane & 15;
    // bijective XCD swizzle over 1024 blocks (8 XCDs x 128 chunks)
    const int lin0 = blockIdx.x;
    const int lin  = ((lin0 & 7) << 7) | (lin0 >> 3);
    const int qt = lin & 15;
    const int bh = lin >> 4;
    const int h  = bh & 31;
    const int b  = bh >> 5;

    const float scale = 0.111803398874989485f;   // 1/sqrt(80)
    const float c2    = scale * scale * is_ptr[0] * (1.0f / 3.0f);
    const float cosph = cosf(qphase[h]);

    if (t < 240) {
        int g = t / 80;
        float r0 = gmats[g*4+0] + gmats[g*4+1];
        float r1 = gmats[g*4+2] + gmats[g*4+3];
        cs[t] = (cosf(gphases[t]) * r0 + sinf(gphases[t]) * r1) * gamps[t];
    }

    const int srow = t >> 2;          // staging row 0..63 (wave w stages rows 16w..16w+15)
    const int scg  = (t & 3) * 20;    // staging col group (20 bf16)

    // V staging mapping (kg-inner, conflict-reduced):
    const int vkg  = t & 15;
    const int vdg0 = t >> 4;

    {   // stage Q tile into Ks + zero the d-pad [80,96)
        const unsigned short* qp = qk + (size_t)(b * S_ + qt * 64 + srow) * QK_ + h * D_ + scg;
#pragma unroll
        for (int u = 0; u < 5; ++u)
            *(ushort4*)&Ks[srow * 104 + scg + 4 * u] = *(const ushort4*)(qp + 4 * u);
        *(ushort4*)&Ks[srow * 104 + 80 + (t & 3) * 4] = (ushort4){0, 0, 0, 0};
    }
    __syncthreads();   // cs + Q visible

    // ---- prefetch tile 0 into registers (overlaps afq/afg build) ----
    ushort4 kpre[5];
    ushort4 vpre[8];
    {
        const unsigned short* kp = qk + (size_t)(b * S_ + srow) * QK_ + E_ + h * D_ + scg;
#pragma unroll
        for (int u = 0; u < 5; ++u) kpre[u] = *(const ushort4*)(kp + 4 * u);
        const unsigned short* vb = vsrc + (size_t)(b * S_) * E_ + h * D_;
#pragma unroll
        for (int i = 0; i < 4; ++i)
            vpre[i] = *(const ushort4*)(vb + (size_t)(vkg * 4 + i) * E_ + vdg0 * 4);
        if (t < 64) {
#pragma unroll
            for (int i = 0; i < 4; ++i)
                vpre[4 + i] = *(const ushort4*)(vb + (size_t)(vkg * 4 + i) * E_ + 64 + vdg0 * 4);
        }
    }

    // A-fragments: base Q + 3 coefficient-scaled variants (persist across k-tiles)
    bf16x8 afq[3], afg[3][3];
#pragma unroll
    for (int kc = 0; kc < 3; ++kc)
        afq[kc] = *(const bf16x8*)&Ks[(wave * 16 + l15) * 104 + quad * 8 + kc * 32];
#pragma unroll
    for (int g = 0; g < 3; ++g)
#pragma unroll
        for (int kc = 0; kc < 3; ++kc)
#pragma unroll
            for (int j = 0; j < 8; ++j) {
                int d = kc * 32 + quad * 8 + j;
                float c = (d < 80) ? cs[g * 80 + d] : 0.f;
                afg[g][kc][j] = (short)f2bf(bf2f((unsigned short)afq[kc][j]) * c);
            }

    f32x4 Ov[5];
#pragma unroll
    for (int nf = 0; nf < 5; ++nf) Ov[nf] = (f32x4){0.f, 0.f, 0.f, 0.f};
    float m_r[4] = {-INFINITY, -INFINITY, -INFINITY, -INFINITY};
    float l_r[4] = {0.f, 0.f, 0.f, 0.f};

    for (int kt = 0; kt < 16; ++kt) {
        __syncthreads();   // prev iter's Ks/Vt/Ps reads complete (iter0: Q-frag reads done)

        // ---- write prefetched K tile [kj][d] into Ks (pad stays 0) ----
#pragma unroll
        for (int u = 0; u < 5; ++u)
            *(ushort4*)&Ks[srow * 104 + scg + 4 * u] = kpre[u];

        // ---- write prefetched V^T [d][kj] via 4x4 in-register transpose ----
        {
            const unsigned short rm[4][4] = {
                {vpre[0].x, vpre[0].y, vpre[0].z, vpre[0].w},
                {vpre[1].x, vpre[1].y, vpre[1].z, vpre[1].w},
                {vpre[2].x, vpre[2].y, vpre[2].z, vpre[2].w},
                {vpre[3].x, vpre[3].y, vpre[3].z, vpre[3].w}};
#pragma unroll
            for (int j = 0; j < 4; ++j) {
                ushort4 w = {rm[0][j], rm[1][j], rm[2][j], rm[3][j]};
                *(ushort4*)&Vt[(vdg0 * 4 + j) * 72 + vkg * 4] = w;
            }
        }
        if (t < 64) {
            const unsigned short rm[4][4] = {
                {vpre[4].x, vpre[4].y, vpre[4].z, vpre[4].w},
                {vpre[5].x, vpre[5].y, vpre[5].z, vpre[5].w},
                {vpre[6].x, vpre[6].y, vpre[6].z, vpre[6].w},
                {vpre[7].x, vpre[7].y, vpre[7].z, vpre[7].w}};
#pragma unroll
            for (int j = 0; j < 4; ++j) {
                ushort4 w = {rm[0][j], rm[1][j], rm[2][j], rm[3][j]};
                *(ushort4*)&Vt[(64 + vdg0 * 4 + j) * 72 + vkg * 4] = w;
            }
        }
        __syncthreads();

        // ---- issue next tile's global loads; latency hides under compute ----
        if (kt < 15) {
            const unsigned short* kp = qk + (size_t)(b * S_ + (kt + 1) * 64 + srow) * QK_ + E_ + h * D_ + scg;
#pragma unroll
            for (int u = 0; u < 5; ++u) kpre[u] = *(const ushort4*)(kp + 4 * u);
            const unsigned short* vb = vsrc + (size_t)(b * S_ + (kt + 1) * 64) * E_ + h * D_;
#pragma unroll
            for (int i = 0; i < 4; ++i)
                vpre[i] = *(const ushort4*)(vb + (size_t)(vkg * 4 + i) * E_ + vdg0 * 4);
            if (t < 64) {
#pragma unroll
                for (int i = 0; i < 4; ++i)
                    vpre[4 + i] = *(const ushort4*)(vb + (size_t)(vkg * 4 + i) * E_ + 64 + vdg0 * 4);
            }
        }

        // ---- score MFMAs in two nf-halves: only sacc[4][2] live at once ----
        float p[4][4];   // [nf][r]
        float mx[4] = {-INFINITY, -INFINITY, -INFINITY, -INFINITY};
#pragma unroll
        for (int hf = 0; hf < 2; ++hf) {
            f32x4 sacc[4][2];
#pragma unroll
            for (int v = 0; v < 4; ++v)
#pragma unroll
                for (int n = 0; n < 2; ++n) sacc[v][n] = (f32x4){0.f, 0.f, 0.f, 0.f};
#pragma unroll
            for (int kc = 0; kc < 3; ++kc) {
                bf16x8 bk[2];
#pragma unroll
                for (int n = 0; n < 2; ++n)
                    bk[n] = *(const bf16x8*)&Ks[((hf * 2 + n) * 16 + l15) * 104 + quad * 8 + kc * 32];
#pragma unroll
                for (int n = 0; n < 2; ++n)
                    sacc[0][n] = __builtin_amdgcn_mfma_f32_16x16x32_bf16(afq[kc], bk[n], sacc[0][n], 0, 0, 0);
#pragma unroll
                for (int g = 0; g < 3; ++g)
#pragma unroll
                    for (int n = 0; n < 2; ++n)
                        sacc[1+g][n] = __builtin_amdgcn_mfma_f32_16x16x32_bf16(afg[g][kc], bk[n], sacc[1+g][n], 0, 0, 0);
            }
#pragma unroll
            for (int n = 0; n < 2; ++n)
#pragma unroll
                for (int r = 0; r < 4; ++r) {
                    float s0 = sacc[1][n][r], s1 = sacc[2][n][r], s2 = sacc[3][n][r];
                    float s = fmaf(fmaf(s0, s1, (s0 + s1) * s2), c2, sacc[0][n][r] * scale);
                    p[hf * 2 + n][r] = s;
                    mx[r] = fmaxf(mx[r], s);
                }
        }

        // ---- online softmax (C layout: row=quad*4+r, col=l15+16nf) ----
#pragma unroll
        for (int r = 0; r < 4; ++r) {
            mx[r] = fmaxf(mx[r], __shfl_xor(mx[r], 1));
            mx[r] = fmaxf(mx[r], __shfl_xor(mx[r], 2));
            mx[r] = fmaxf(mx[r], __shfl_xor(mx[r], 4));
            mx[r] = fmaxf(mx[r], __shfl_xor(mx[r], 8));
        }
        float alpha[4];
#pragma unroll
        for (int r = 0; r < 4; ++r) {
            float m_new = fmaxf(m_r[r], mx[r]);
            alpha[r] = __expf(m_r[r] - m_new);
            m_r[r] = m_new;
        }
#pragma unroll
        for (int nf = 0; nf < 4; ++nf)
#pragma unroll
            for (int r = 0; r < 4; ++r)
                p[nf][r] = __expf(p[nf][r] - m_r[r]);
#pragma unroll
        for (int r = 0; r < 4; ++r) {
            float s = p[0][r] + p[1][r] + p[2][r] + p[3][r];
            s += __shfl_xor(s, 1);
            s += __shfl_xor(s, 2);
            s += __shfl_xor(s, 4);
            s += __shfl_xor(s, 8);
            l_r[r] = l_r[r] * alpha[r] + s;
        }

        // ---- write P (bf16) to LDS; own-wave rows only ----
#pragma unroll
        for (int nf = 0; nf < 4; ++nf)
#pragma unroll
            for (int r = 0; r < 4; ++r)
                Ps[(wave * 16 + quad * 4 + r) * 72 + l15 + 16 * nf] = f2bf(p[nf][r]);
        __asm__ volatile("s_waitcnt lgkmcnt(0)" ::: "memory");

        // ---- O rescale + PV MFMAs ----
#pragma unroll
        for (int nf = 0; nf < 5; ++nf)
#pragma unroll
            for (int r = 0; r < 4; ++r) Ov[nf][r] *= alpha[r];

        bf16x8 ap[2];
#pragma unroll
        for (int kc = 0; kc < 2; ++kc)
            ap[kc] = *(const bf16x8*)&Ps[(wave * 16 + l15) * 72 + quad * 8 + kc * 32];
#pragma unroll
        for (int nf = 0; nf < 5; ++nf)
#pragma unroll
            for (int kc = 0; kc < 2; ++kc) {
                bf16x8 bv = *(const bf16x8*)&Vt[(nf * 16 + l15) * 72 + quad * 8 + kc * 32];
                Ov[nf] = __builtin_amdgcn_mfma_f32_16x16x32_bf16(ap[kc], bv, Ov[nf], 0, 0, 0);
            }
    }

    // ---- epilogue: O * cos(phase)/l -> Q section of qk (bf16) ----
    float inv[4];
#pragma unroll
    for (int r = 0; r < 4; ++r) inv[r] = cosph / l_r[r];
#pragma unroll
    for (int nf = 0; nf < 5; ++nf)
#pragma unroll
        for (int r = 0; r < 4; ++r)
            qk[(size_t)(b * S_ + qt * 64 + wave * 16 + quad * 4 + r) * QK_ + h * D_ + nf * 16 + l15]
                = f2bf(Ov[nf][r] * inv[r]);
}

extern "C" void kernel_launch(void* const* d_in, const int* in_sizes, int n_in,
                              void* d_out, int out_size, void* d_ws, size_t ws_size,
                              hipStream_t stream) {
    (void)in_sizes; (void)n_in; (void)out_size; (void)ws_size;
    const float* hidden  = (const float*)d_in[0];
    const float* Wqkv    = (const float*)d_in[1];
    const float* bqkv    = (const float*)d_in[2];
    const float* Wproj   = (const float*)d_in[3];
    const float* bproj   = (const float*)d_in[4];
    const float* gmats   = (const float*)d_in[5];
    const float* gphases = (const float*)d_in[6];
    const float* gamps   = (const float*)d_in[7];
    const float* qphase  = (const float*)d_in[8];
    const float* is_ptr  = (const float*)d_in[9];

    // ws layout (70.8 MB): qk_ws 21.0 MB | h_bf16 10.5 MB | Wt 39.3 MB (reused for Wproj_t)
    unsigned short* qk_ws  = (unsigned short*)d_ws;
    unsigned short* h_bf16 = (unsigned short*)((char*)d_ws + (size_t)M_ * QK_ * 2);
    unsigned short* Wt     = (unsigned short*)((char*)d_ws + (size_t)M_ * QK_ * 2 + (size_t)M_ * E_ * 2);
    unsigned short* v_buf  = (unsigned short*)d_out;   // V bf16 parked in d_out (consumed by attn)

    dim3 blk(256);
    cvt_bf16_kernel<<<dim3((M_ * E_ / 8 + 255) / 256), blk, 0, stream>>>(hidden, h_bf16, M_ * E_ / 8);
    transpose_bf16_kernel<<<dim3(E3_/64, E_/64), blk, 0, stream>>>(Wqkv, Wt, E_, E3_);
    mfma_gemm256_kernel<<<dim3(E3_/256, M_/256), dim3(512), 0, stream>>>(
        h_bf16, E_, Wt, bqkv, qk_ws, QK_, v_buf, E_, QK_, E_);
    attn_mfma_kernel<<<dim3(2 * H_ * (S_/64)), blk, 0, stream>>>(
        qk_ws, v_buf, gmats, gphases, gamps, qphase, is_ptr);
    transpose_bf16_kernel<<<dim3(E_/64, E_/64), blk, 0, stream>>>(Wproj, Wt, E_, E_);
    mfma_gemm_proj_kernel<<<dim3(E_/128, M_/128), dim3(512), 0, stream>>>(
        qk_ws, QK_, Wt, bproj, (float*)d_out, E_, E_);
}